// Round 1
// baseline (6991.325 us; speedup 1.0000x reference)
//
#include <hip/hip_runtime.h>
#include <hip/hip_bf16.h>

// Problem dims (fixed by the reference)
#define BB 4        // batch
#define CC 4096     // channels (river nodes)
#define TT 2048     // timesteps
#define BS 16       // block size
#define KK 100      // IRF taps
#define NNZ 1024    // nonzero blocks
#define NB (CC / BS)

// ---------------- identity copy: out = runoff ----------------
__global__ void lti_copy_kernel(const float4* __restrict__ in,
                                float4* __restrict__ out, int n4) {
    int idx = blockIdx.x * blockDim.x + threadIdx.x;
    if (idx < n4) out[idx] = in[idx];
}

// ---------------- DPP helpers: reduce over low 4 lane bits ----------------
template <int CTRL>
__device__ __forceinline__ float dpp_add(float v) {
    int perm = __builtin_amdgcn_update_dpp(0, __builtin_bit_cast(int, v),
                                           CTRL, 0xF, 0xF, true);
    return v + __builtin_bit_cast(float, perm);
}

__device__ __forceinline__ float reduce16(float v) {
    v = dpp_add<0xB1>(v);   // quad_perm [1,0,3,2]  : xor 1
    v = dpp_add<0x4E>(v);   // quad_perm [2,3,0,1]  : xor 2
    v = dpp_add<0x140>(v);  // row_mirror           : xor 15 (crosses quads)
    v = dpp_add<0x141>(v);  // row_half_mirror      : xor 7
    return v;               // all 16 lanes hold the sum
}

// ---------------- router: one WG per (block n, batch b) ----------------
__global__ __launch_bounds__(256) void lti_router_kernel(
    const float* __restrict__ x,       // [B, C, T]
    const float* __restrict__ params,  // [NNZ, BS, BS]
    const int* __restrict__ rows,      // [NNZ]
    const int* __restrict__ cols,      // [NNZ]
    float* __restrict__ out)           // [B, C, T]
{
    const int n = blockIdx.x;
    const int b = blockIdx.y;
    const int tid = threadIdx.x;
    const int i = tid >> 4;
    const int j = tid & 15;

    const int c = cols[n];
    const int r = rows[n];

    // per-entry IRF params
    const float p = params[n * (BS * BS) + tid];
    const float tau = 1.0f + 19.0f * p;
    const float a   = expf(-1.0f / tau);
    const float aK  = expf(-(float)KK / tau);
    const float oma = 1.0f - a;

    const float* __restrict__ xblk = x + ((size_t)b * CC + (size_t)c * BS) * TT;
    float* __restrict__ yrow = out + ((size_t)b * CC + (size_t)r * BS + i) * TT;

    // ring buffer: 16 rows x 256 timesteps, stride 257 to spread banks
    __shared__ float xs[16 * 257];
    const int base = j * 257;

    float s = 0.0f;

    for (int t0 = 0; t0 < TT; t0 += 128) {
        // stage x[*, t0 .. t0+128) into the ring (coalesced per row)
        #pragma unroll
        for (int k = 0; k < 8; ++k) {
            int idx = tid + k * 256;          // 0 .. 2047
            int row = idx >> 7;               // 0 .. 15
            int col = idx & 127;              // 0 .. 127
            int tt = t0 + col;
            xs[row * 257 + (tt & 255)] = xblk[(size_t)row * TT + tt];
        }
        __syncthreads();

        #pragma unroll 4
        for (int t = t0; t < t0 + 128; ++t) {
            float xc = xs[base + (t & 255)];
            float xold = (t >= KK) ? xs[base + ((t - KK) & 255)] : 0.0f;
            // s = a*s + xc - aK*xold   (exact truncated K-tap conv)
            s = fmaf(a, s, fmaf(-aK, xold, xc));
            float v = oma * s;
            v = reduce16(v);                  // sum over j (low 4 lane bits)
            if (j == 0) atomicAdd(yrow + t, v);
        }
        __syncthreads();
    }
}

extern "C" void kernel_launch(void* const* d_in, const int* in_sizes, int n_in,
                              void* d_out, int out_size, void* d_ws, size_t ws_size,
                              hipStream_t stream) {
    const float* runoff = (const float*)d_in[0];
    const float* params = (const float*)d_in[1];
    const int* rows = (const int*)d_in[2];
    const int* cols = (const int*)d_in[3];
    float* out = (float*)d_out;

    // 1) out = runoff
    const int n4 = (BB * CC * TT) / 4;
    lti_copy_kernel<<<n4 / 256, 256, 0, stream>>>(
        (const float4*)runoff, (float4*)out, n4);

    // 2) block-sparse IIR routing, atomic row scatter-add
    dim3 grid(NNZ, BB);
    lti_router_kernel<<<grid, 256, 0, stream>>>(runoff, params, rows, cols, out);
}

// Round 2
// 945.711 us; speedup vs baseline: 7.3927x; 7.3927x over previous
//
#include <hip/hip_runtime.h>
#include <hip/hip_bf16.h>

// Problem dims (fixed by the reference)
#define BB 4        // batch
#define CC 4096     // channels (river nodes)
#define TT 2048     // timesteps
#define BS 16       // block size
#define KK 100      // IRF taps
#define NNZ 1024    // nonzero blocks
#define NB (CC / BS)

#define TC 128              // timestep chunk per WG
#define NCH (TT / TC)       // 16 chunks
#define WIN (TC + KK)       // 228 staged floats per row
#define XS_STRIDE (WIN + 1) // 229 (odd) -> bank-conflict-free column reads
#define MAXM 64             // max blocks per output row (P(exceed) ~ 0)

// ---------------- DPP helpers: reduce over low 4 lane bits ----------------
template <int CTRL>
__device__ __forceinline__ float dpp_add(float v) {
    int perm = __builtin_amdgcn_update_dpp(0, __builtin_bit_cast(int, v),
                                           CTRL, 0xF, 0xF, true);
    return v + __builtin_bit_cast(float, perm);
}

__device__ __forceinline__ float reduce16(float v) {
    v = dpp_add<0xB1>(v);   // quad_perm xor 1
    v = dpp_add<0x4E>(v);   // quad_perm xor 2
    v = dpp_add<0x140>(v);  // row_mirror      (xor 15 -> adds quad^3)
    v = dpp_add<0x141>(v);  // row_half_mirror (xor 7  -> adds quad^1,^2)
    return v;               // all 16 lanes of the j-group hold the sum
}

// ------------- prep: per-row block lists, deterministic (no atomics) -------
__global__ void lti_build_lists(const int* __restrict__ rows,
                                int* __restrict__ cnt,
                                int* __restrict__ list) {
    int r = threadIdx.x;            // one thread per output row, single WG
    if (r >= NB) return;
    int m = 0;
    for (int n = 0; n < NNZ; ++n) {
        if (rows[n] == r && m < MAXM) {
            list[r * MAXM + m] = n;
            ++m;
        }
    }
    cnt[r] = m;
}

// ------------- router: one WG per (output row-block r, batch b, t-chunk) ---
// Exclusive ownership of out[b, r*16..r*16+16, t0..t0+TC): no atomics.
__global__ __launch_bounds__(256) void lti_router(
    const float* __restrict__ x,       // runoff [B, C, T]
    const float* __restrict__ params,  // [NNZ, BS, BS]
    const int* __restrict__ cols,      // [NNZ]
    const int* __restrict__ cnt,       // [NB]
    const int* __restrict__ list,      // [NB, MAXM]
    float* __restrict__ out)           // [B, C, T]
{
    const int r   = blockIdx.x;
    const int b   = blockIdx.y;
    const int t0  = blockIdx.z * TC;
    const int tid = threadIdx.x;
    const int j   = tid & 15;          // input row within block
    const int i   = tid >> 4;          // output row within block

    __shared__ float xs[16 * XS_STRIDE];

    // register accumulator: thread (i,j) owns y[i][tb*16 + j], tb = 0..7
    float acc[8];
    #pragma unroll
    for (int k = 0; k < 8; ++k) acc[k] = 0.0f;

    const int m = cnt[r];
    for (int bi = 0; bi < m; ++bi) {
        const int n = list[r * MAXM + bi];
        const int c = cols[n];

        // stage x[b, c*16 + row, t0-KK .. t0+TC) ; t<0 -> 0
        const float* __restrict__ xb =
            x + ((size_t)b * CC + (size_t)c * BS) * TT;
        if (tid < WIN) {
            const int t = t0 - KK + tid;
            #pragma unroll
            for (int row = 0; row < 16; ++row) {
                float v = (t >= 0) ? xb[(size_t)row * TT + t] : 0.0f;
                xs[row * XS_STRIDE + tid] = v;
            }
        }
        __syncthreads();

        // per-entry IRF params (inline: ~1% of per-visit work)
        const float p   = params[n * (BS * BS) + tid];
        const float tau = 1.0f + 19.0f * p;
        const float a   = expf(-1.0f / tau);
        const float aK  = expf(-(float)KK / tau);
        const float oma = 1.0f - a;

        const float* __restrict__ xj = &xs[j * XS_STRIDE];

        // bootstrap state: s[t0-1] = sum_{k=0..99} a^k x[t0-1-k]  (Horner)
        float s = 0.0f;
        #pragma unroll 4
        for (int k = 0; k < KK; ++k) s = fmaf(a, s, xj[k]);

        // main recursion over the chunk (exact truncated K-tap conv):
        //   s[t] = a*s[t-1] + x[t] - a^K * x[t-K]; y[t] = (1-a)*s[t]
        #pragma unroll
        for (int tb = 0; tb < 8; ++tb) {
            #pragma unroll
            for (int tt = 0; tt < 16; ++tt) {
                const int tl = tb * 16 + tt;
                const float xc = xj[KK + tl];
                const float xo = xj[tl];
                s = fmaf(a, s, fmaf(-aK, xo, xc));
                float v = oma * s;
                v = reduce16(v);
                if (j == tt) acc[tb] += v;   // static acc index (unrolled)
            }
        }
        __syncthreads();   // before next block overwrites xs
    }

    // epilogue: out = runoff + y, coalesced, written exactly once
    const size_t obase = ((size_t)b * CC + (size_t)r * BS + i) * TT + t0;
    #pragma unroll
    for (int tb = 0; tb < 8; ++tb) {
        const size_t idx = obase + tb * 16 + j;
        out[idx] = x[idx] + acc[tb];
    }
}

extern "C" void kernel_launch(void* const* d_in, const int* in_sizes, int n_in,
                              void* d_out, int out_size, void* d_ws, size_t ws_size,
                              hipStream_t stream) {
    const float* runoff = (const float*)d_in[0];
    const float* params = (const float*)d_in[1];
    const int* rows = (const int*)d_in[2];
    const int* cols = (const int*)d_in[3];
    float* out = (float*)d_out;

    // ws layout: cnt [NB] ints @ 0, list [NB*MAXM] ints @ 1024 bytes
    int* cnt  = (int*)d_ws;
    int* list = (int*)((char*)d_ws + 1024);

    lti_build_lists<<<1, 256, 0, stream>>>(rows, cnt, list);

    dim3 grid(NB, BB, NCH);
    lti_router<<<grid, 256, 0, stream>>>(runoff, params, cols, cnt, list, out);
}